// Round 2
// baseline (144.107 us; speedup 1.0000x reference)
//
#include <hip/hip_runtime.h>
#include <hip/hip_bf16.h>

#define N_PIX 8192
#define C_DIM 128
#define HW 4096
// exp(dot/0.1) = exp2(dot * 14.42695...); fold sqrt of that into each vector.
#define PRESCALE 3.7982825f  // sqrt(log2(e)/0.1)
#define NUM_CLASSES 4
#define PAIR_BLOCKS (64 * 16)

typedef __attribute__((ext_vector_type(8))) short short8;   // 8 x bf16 (4 VGPRs)
typedef __attribute__((ext_vector_type(4))) float float4v;  // 4 x f32 acc

// Fragment-linear layout (R7 win): ebfT[((T*4 + s)*64 + lane)*8 + j] = e[T*16 + lq][s*32 + quad*8 + j],
// lane = quad*16 + lq. Fragment load = base + lane*16B: one coalesced 1KB dwordx4.

// ---------------- Kernel 1: L2-normalize + prescale + bf16 cast into ebfT; zero pos/tot/counter ----------------
__global__ __launch_bounds__(256) void normscale_kernel(const float* __restrict__ emb,
                                                        unsigned short* __restrict__ ebfT,
                                                        float* __restrict__ pz,
                                                        unsigned* __restrict__ cnt) {
    const int tid = threadIdx.x;
    const int p16 = tid & 15;   // pixel within tile (lq)
    const int g = tid >> 4;     // channel group 0..15 (8 channels each)
    const int n = blockIdx.x * 16 + p16;
    const int b = n >> 12;
    const int hw = n & (HW - 1);
    const float* base = emb + b * (C_DIM * HW) + hw;

    float v[8];
    float ss = 0.f;
#pragma unroll
    for (int i = 0; i < 8; ++i) {
        v[i] = base[(g * 8 + i) * HW];
        ss += v[i] * v[i];
    }
    ss += __shfl_xor(ss, 16, 64);
    ss += __shfl_xor(ss, 32, 64);
    __shared__ float red[4][16];
    const int wv = tid >> 6;
    if ((tid & 63) < 16) red[wv][p16] = ss;
    __syncthreads();
    float tot = red[0][p16] + red[1][p16] + red[2][p16] + red[3][p16];
    float inv = PRESCALE / fmaxf(sqrtf(tot), 1e-12f);

    unsigned short us[8];
#pragma unroll
    for (int i = 0; i < 8; ++i) {
        __hip_bfloat16 h = __float2bfloat16(v[i] * inv);
        us[i] = *reinterpret_cast<unsigned short*>(&h);
    }
    const int s = g >> 2, quad = g & 3;
    unsigned short* dst = ebfT + (((blockIdx.x * 4 + s) * 64 + quad * 16 + p16) << 3);
    *reinterpret_cast<short8*>(dst) = *reinterpret_cast<short8*>(us);

    if (blockIdx.x < 64) pz[blockIdx.x * 256 + tid] = 0.f;
    if (blockIdx.x == 64 && tid == 0) cnt[0] = 0u;
}

// ---------------- Kernel 2: symmetric fused S = e e^T, exp2, row+col sums, fused finalize ----------------
// R15 (this round): blocks widened to 128 rows x 256 cols (two J panels per block).
//   Grid (64,16): bi = I panel, dd -> d = 2dd+1 and 2dd+2 (d spans 1..32 as before).
//   d=1..31 covers each unordered off-diag panel pair once; d=32 double-covers -> the
//   (dd==15, bi>=32) blocks skip their second panel (partial cull, block still runs).
//   Effect: block count 2048->1024 (exactly one occupancy round at 4 blocks/CU),
//   row-side atomic lane-ops HALVED (one flush per 2 panels), A-frags/labels/prologue
//   amortized 2x. Diag phase2 stays on dd==0 blocks (they run 3 panel-works; they
//   launch first so the scheduler packs them well).
// R15b: finalize fused via last-block completion counter (saves a launch + gap; the
//   last block reads pos/tot with agent-scope loads straight from the coherence point).
// R14: col-side partials go to LDS per tile (fire-and-forget ds_write_b64), reduced
//   once per block after ONE __syncthreads, one atomic per column per block.
// HARD-WON toolchain rules:
//   *** NEVER fully `#pragma unroll` the MFMA tile loop *** — hoists all B-tile loads
//   -> forced spill (VGPR 64 + FETCH/WRITE >100MB signature; R6/R10/R11/R12).
//   `#pragma unroll 2` keeps only 2 tiles in flight (~+16 VGPRs) for load/compute overlap.
//   R3: (256,8) caps VGPR -> spill; keep (256,4).
//   R5: global_load_lds on cache-resident input explodes HBM traffic -> plain loads.
//   R6: no lambdas; reg arrays statically indexed only (LDS arrays may be runtime-indexed).
//   R13: store-partials+reduce-kernel alternative to atomics is 6us WORSE.
__global__ __launch_bounds__(256, 4) void pairwise_kernel(const unsigned short* __restrict__ ebfT,
                                                          const int* __restrict__ lab,
                                                          float* __restrict__ pos,
                                                          float* __restrict__ tot,
                                                          unsigned* __restrict__ cnt,
                                                          float* __restrict__ out) {
    const int bi = blockIdx.x;     // I panel 0..63
    const int dd = blockIdx.y;     // 0..15

    const int wave = threadIdx.x >> 6;
    const int lane = threadIdx.x & 63;
    const int quad = lane >> 4;
    const int lq = lane & 15;

    const int Ipanel = bi << 7;
    const int I0 = Ipanel + wave * 32;
    const bool has2 = !(dd == 15 && bi >= 32);  // second-panel cull (block-uniform)

    // [wave][tile 0..15][lane] col-side partials (x=tot, y=pos). 32 KiB.
    __shared__ float2 cpart[4][16][64];

    // A fragments: tiles (I0>>4), (I0>>4)+1 — coalesced lane*16B loads.
    short8 afrag[2][4];
#pragma unroll
    for (int a = 0; a < 2; ++a) {
        const unsigned short* ab = ebfT + ((((I0 >> 4) + a) * 4) * 64 + lane) * 8;
#pragma unroll
        for (int s = 0; s < 4; ++s)
            afrag[a][s] = *reinterpret_cast<const short8*>(ab + s * 512);
    }
    int lab_row[2][4];
#pragma unroll
    for (int a = 0; a < 2; ++a)
#pragma unroll
        for (int r = 0; r < 4; ++r) lab_row[a][r] = lab[I0 + a * 16 + quad * 4 + r];

    float tacc[2][4] = {};
    float pacc[2][4] = {};

    // ---- Phase 1: two off-diagonal panel pairs (no masking, row + col side) ----
    for (int pp = 0; pp < 2; ++pp) {
        if (pp == 1 && !has2) break;
        const int jp = (bi + 2 * dd + 1 + pp) & 63;
        const int Jpanel = jp << 7;
        const unsigned short* bbase = ebfT + ((Jpanel >> 4) * 4 * 64 + lane) * 8;
#pragma unroll 2
        for (int t = 0; t < 8; ++t) {
            const int lab_col = lab[Jpanel + t * 16 + lq];
            const unsigned short* bt = bbase + t * 2048;
            short8 bfrag[4];
#pragma unroll
            for (int s = 0; s < 4; ++s)
                bfrag[s] = *reinterpret_cast<const short8*>(bt + s * 512);

            float4v acc0 = {0.f, 0.f, 0.f, 0.f};
            float4v acc1 = {0.f, 0.f, 0.f, 0.f};
#pragma unroll
            for (int s = 0; s < 4; ++s) {
                acc0 = __builtin_amdgcn_mfma_f32_16x16x32_bf16(afrag[0][s], bfrag[s], acc0, 0, 0, 0);
                acc1 = __builtin_amdgcn_mfma_f32_16x16x32_bf16(afrag[1][s], bfrag[s], acc1, 0, 0, 0);
            }

            float colTs = 0.f, colPs = 0.f;
#pragma unroll
            for (int r = 0; r < 4; ++r) {
                float ex = __builtin_amdgcn_exp2f(acc0[r]);
                tacc[0][r] += ex;
                float pxe = (lab_row[0][r] == lab_col) ? ex : 0.f;
                pacc[0][r] += pxe;
                colTs += ex;
                colPs += pxe;
            }
#pragma unroll
            for (int r = 0; r < 4; ++r) {
                float ex = __builtin_amdgcn_exp2f(acc1[r]);
                tacc[1][r] += ex;
                float pxe = (lab_row[1][r] == lab_col) ? ex : 0.f;
                pacc[1][r] += pxe;
                colTs += ex;
                colPs += pxe;
            }
            // fire-and-forget ds_write_b64; reduction deferred to post-barrier gather.
            cpart[wave][pp * 8 + t][lane] = make_float2(colTs, colPs);
        }
    }

    // ---- Phase 2 (dd==0 blocks only): diagonal panel bi, self-masked, row-side only ----
#define EPILOGUE(A, ACC, MASKED)                                            \
    {                                                                       \
        _Pragma("unroll") for (int r = 0; r < 4; ++r) {                     \
            float ex = __builtin_amdgcn_exp2f(ACC[r]);                      \
            if (MASKED) ex = (lq == quad * 4 + r) ? 0.f : ex;               \
            tacc[A][r] += ex;                                               \
            pacc[A][r] += (lab_row[A][r] == lab_col) ? ex : 0.f;            \
        }                                                                   \
    }
    if (dd == 0) {
        const unsigned short* bbase = ebfT + ((Ipanel >> 4) * 4 * 64 + lane) * 8;
#pragma unroll 2
        for (int t = 0; t < 8; ++t) {
            const int J = Ipanel + t * 16;
            const int lab_col = lab[J + lq];
            const unsigned short* bt = bbase + t * 2048;
            short8 bfrag[4];
#pragma unroll
            for (int s = 0; s < 4; ++s)
                bfrag[s] = *reinterpret_cast<const short8*>(bt + s * 512);

            float4v acc0 = {0.f, 0.f, 0.f, 0.f};
            float4v acc1 = {0.f, 0.f, 0.f, 0.f};
#pragma unroll
            for (int s = 0; s < 4; ++s) {
                acc0 = __builtin_amdgcn_mfma_f32_16x16x32_bf16(afrag[0][s], bfrag[s], acc0, 0, 0, 0);
                acc1 = __builtin_amdgcn_mfma_f32_16x16x32_bf16(afrag[1][s], bfrag[s], acc1, 0, 0, 0);
            }
            if (J == I0) EPILOGUE(0, acc0, true) else EPILOGUE(0, acc0, false);
            if (J == I0 + 16) EPILOGUE(1, acc1, true) else EPILOGUE(1, acc1, false);
        }
    }
#undef EPILOGUE

    // ---- Row-side flush (covers both panels + phase 2): one atomic per row per block ----
    // Register-only + shfl; independent of the barrier, so done BEFORE __syncthreads.
#pragma unroll
    for (int a = 0; a < 2; ++a) {
#pragma unroll
        for (int r = 0; r < 4; ++r) {
            float t = tacc[a][r], p = pacc[a][r];
#pragma unroll
            for (int off = 1; off < 16; off <<= 1) {
                t += __shfl_xor(t, off, 64);
                p += __shfl_xor(p, off, 64);
            }
            if (lq == 0) {
                const int row = I0 + a * 16 + quad * 4 + r;
                atomicAdd(&tot[row], t);
                atomicAdd(&pos[row], p);
            }
        }
    }

    // ---- Col-side gather: sum 4 waves x 4 quads per column, one atomic per column ----
    __syncthreads();
    {
        const int j = threadIdx.x;          // 0..255 -> column within the two J panels
        const int pp = j >> 7;
        if (pp == 0 || has2) {
            const int jc = j & 127;
            const int jp = (bi + 2 * dd + 1 + pp) & 63;
            const int tt = pp * 8 + (jc >> 4);
            const int jl = jc & 15;
            float st = 0.f, sp = 0.f;
#pragma unroll
            for (int w = 0; w < 4; ++w)
#pragma unroll
                for (int q = 0; q < 4; ++q) {
                    float2 v = cpart[w][tt][q * 16 + jl];
                    st += v.x;
                    sp += v.y;
                }
            atomicAdd(&tot[(jp << 7) + jc], st);
            atomicAdd(&pos[(jp << 7) + jc], sp);
        }
    }

    // ---- R15b: last block inlines the finalize ----
    __threadfence();
    __syncthreads();
    __shared__ unsigned slast;
    if (threadIdx.x == 0)
        slast = (atomicAdd(cnt, 1u) == PAIR_BLOCKS - 1) ? 1u : 0u;
    __syncthreads();
    if (slast == 0u) return;

    {
        const int tid = threadIdx.x;
        float ls[NUM_CLASSES] = {0.f, 0.f, 0.f, 0.f};
        float lc[NUM_CLASSES] = {0.f, 0.f, 0.f, 0.f};
#pragma unroll
        for (int it = 0; it < N_PIX / 256; ++it) {
            const int n = it * 256 + tid;
            float tv = __hip_atomic_load(&tot[n], __ATOMIC_RELAXED, __HIP_MEMORY_SCOPE_AGENT);
            float pv = __hip_atomic_load(&pos[n], __ATOMIC_RELAXED, __HIP_MEMORY_SCOPE_AGENT);
            float rl = logf(tv + 1e-6f) - logf(pv);
            int c = lab[n];
#pragma unroll
            for (int k = 0; k < NUM_CLASSES; ++k) {
                if (c == k) {
                    ls[k] += rl;
                    lc[k] += 1.f;
                }
            }
        }
#pragma unroll
        for (int off = 1; off < 64; off <<= 1) {
#pragma unroll
            for (int k = 0; k < NUM_CLASSES; ++k) {
                ls[k] += __shfl_xor(ls[k], off, 64);
                lc[k] += __shfl_xor(lc[k], off, 64);
            }
        }
        __shared__ float fsum[4][NUM_CLASSES];
        __shared__ float fcnt[4][NUM_CLASSES];
        if ((tid & 63) == 0) {
#pragma unroll
            for (int k = 0; k < NUM_CLASSES; ++k) {
                fsum[wave][k] = ls[k];
                fcnt[wave][k] = lc[k];
            }
        }
        __syncthreads();
        if (tid == 0) {
            float acc = 0.f;
            int present = 0;
            for (int k = 0; k < NUM_CLASSES; ++k) {
                float s = 0.f, c = 0.f;
                for (int w = 0; w < 4; ++w) {
                    s += fsum[w][k];
                    c += fcnt[w][k];
                }
                if (c > 0.f) {
                    acc += s / c;
                    present++;
                }
            }
            out[0] = acc / (float)(present > 0 ? present : 1);
        }
    }
}

extern "C" void kernel_launch(void* const* d_in, const int* in_sizes, int n_in,
                              void* d_out, int out_size, void* d_ws, size_t ws_size,
                              hipStream_t stream) {
    const float* emb = (const float*)d_in[0];  // [2,128,64,64] fp32
    const int* lab = (const int*)d_in[1];      // [2,64,64] int32
    float* out = (float*)d_out;

    unsigned short* ebfT = (unsigned short*)d_ws;            // 2 MiB
    float* pos = (float*)((char*)d_ws + N_PIX * C_DIM * 2);  // [8192] f32
    float* tot = pos + N_PIX;                                // [8192] f32 (contiguous)
    unsigned* cnt = (unsigned*)(tot + N_PIX);                // completion counter

    normscale_kernel<<<N_PIX / 16, 256, 0, stream>>>(emb, ebfT, pos, cnt);

    dim3 grid(64, 16);  // 128-row x 256-col panel-pair cover (one occupancy round)
    pairwise_kernel<<<grid, 256, 0, stream>>>(ebfT, lab, pos, tot, cnt, out);
}

// Round 3
// 87.653 us; speedup vs baseline: 1.6441x; 1.6441x over previous
//
#include <hip/hip_runtime.h>
#include <hip/hip_bf16.h>

#define N_PIX 8192
#define C_DIM 128
#define HW 4096
// exp(dot/0.1) = exp2(dot * 14.42695...); fold sqrt of that into each vector.
#define PRESCALE 3.7982825f  // sqrt(log2(e)/0.1)
#define NUM_CLASSES 4

typedef __attribute__((ext_vector_type(8))) short short8;   // 8 x bf16 (4 VGPRs)
typedef __attribute__((ext_vector_type(4))) float float4v;  // 4 x f32 acc

// Fragment-linear layout (R7 win): ebfT[((T*4 + s)*64 + lane)*8 + j] = e[T*16 + lq][s*32 + quad*8 + j],
// lane = quad*16 + lq. Fragment load = base + lane*16B: one coalesced 1KB dwordx4.

// ---------------- Kernel 1: L2-normalize + prescale + bf16 cast into ebfT; zero pos/tot ----------------
__global__ __launch_bounds__(256) void normscale_kernel(const float* __restrict__ emb,
                                                        unsigned short* __restrict__ ebfT,
                                                        float* __restrict__ pz) {
    const int tid = threadIdx.x;
    const int p16 = tid & 15;   // pixel within tile (lq)
    const int g = tid >> 4;     // channel group 0..15 (8 channels each)
    const int n = blockIdx.x * 16 + p16;
    const int b = n >> 12;
    const int hw = n & (HW - 1);
    const float* base = emb + b * (C_DIM * HW) + hw;

    float v[8];
    float ss = 0.f;
#pragma unroll
    for (int i = 0; i < 8; ++i) {
        v[i] = base[(g * 8 + i) * HW];
        ss += v[i] * v[i];
    }
    ss += __shfl_xor(ss, 16, 64);
    ss += __shfl_xor(ss, 32, 64);
    __shared__ float red[4][16];
    const int wv = tid >> 6;
    if ((tid & 63) < 16) red[wv][p16] = ss;
    __syncthreads();
    float tot = red[0][p16] + red[1][p16] + red[2][p16] + red[3][p16];
    float inv = PRESCALE / fmaxf(sqrtf(tot), 1e-12f);

    unsigned short us[8];
#pragma unroll
    for (int i = 0; i < 8; ++i) {
        __hip_bfloat16 h = __float2bfloat16(v[i] * inv);
        us[i] = *reinterpret_cast<unsigned short*>(&h);
    }
    const int s = g >> 2, quad = g & 3;
    unsigned short* dst = ebfT + (((blockIdx.x * 4 + s) * 64 + quad * 16 + p16) << 3);
    *reinterpret_cast<short8*>(dst) = *reinterpret_cast<short8*>(us);

    if (blockIdx.x < 64) pz[blockIdx.x * 256 + tid] = 0.f;
}

// ---------------- Kernel 2: symmetric fused S = e e^T, exp2, row+col sums ----------------
// Grid (64, 32): bi = I-panel (128 rows), d = blockIdx.y+1 in 1..32; jp = (bi+d)%64.
// d=1..31 covers each unordered off-diag panel pair once; d=32 double-covers -> bi>=32 culled.
// R14: col-side partials -> LDS per tile (fire-and-forget ds_write_b64), reduced once per
//   block after ONE __syncthreads, one atomic per column per block.
// R15 FAILED (144us, pairwise alone 91us): (a) fused finalize used __threadfence = agent-scope
//   release = per-block L2 writeback+INVALIDATE on gfx950 (XCD L2s non-coherent) -> poisoned
//   ebfT L2 reuse for all in-flight blocks; (b) 2-panel blocks on an exactly-one-round grid made
//   the 3-panel dd==0 blocks the dispatch critical path (24 tiles vs 16). REVERTED both.
// R16 (this round): manual register double-buffer of B fragments + lab_col. R15's counters
//   (VGPR=56) showed the compiler was NOT keeping a 2nd B tile in flight despite
//   `#pragma unroll 2` -> ~200cy L2 latency exposed per tile. Explicit bA/bB named buffers,
//   prologue load, next-tile loads ISSUED BEFORE current-tile MFMA/epilogue, `#pragma unroll 1`
//   on the tile loop (prevents the hoist-all-loads spill trap).
// HARD-WON toolchain rules:
//   *** NEVER fully `#pragma unroll` the MFMA tile loop *** — hoists all B-tile loads
//   -> forced spill (R6/R10/R11/R12).
//   R3: (256,8) caps VGPR -> spill; keep (256,4).
//   R5: global_load_lds on cache-resident input explodes HBM traffic -> plain loads.
//   R6: no lambdas; reg arrays statically indexed only (LDS arrays may be runtime-indexed).
//   R13: store-partials+reduce-kernel alternative to atomics is 6us WORSE.
//   R15: NO __threadfence / device-scope fences in or around the hot loop.
__global__ __launch_bounds__(256, 4) void pairwise_kernel(const unsigned short* __restrict__ ebfT,
                                                          const int* __restrict__ lab,
                                                          float* __restrict__ pos,
                                                          float* __restrict__ tot) {
    const int bi = blockIdx.x;
    const int d = blockIdx.y + 1;          // 1..32
    if (d == 32 && bi >= 32) return;       // wrap double-cover cull (block-uniform)
    const int jp = (bi + d) & 63;
    const int Ipanel = bi << 7;
    const int Jpanel = jp << 7;

    const int wave = threadIdx.x >> 6;
    const int lane = threadIdx.x & 63;
    const int quad = lane >> 4;
    const int lq = lane & 15;

    const int I0 = Ipanel + wave * 32;

    // [wave][tile][lane] col-side partials (x=tot, y=pos). 16 KiB.
    __shared__ float2 cpart[4][8][64];

    // A fragments: tiles (I0>>4), (I0>>4)+1 — coalesced lane*16B loads.
    short8 afrag[2][4];
#pragma unroll
    for (int a = 0; a < 2; ++a) {
        const unsigned short* ab = ebfT + ((((I0 >> 4) + a) * 4) * 64 + lane) * 8;
#pragma unroll
        for (int s = 0; s < 4; ++s)
            afrag[a][s] = *reinterpret_cast<const short8*>(ab + s * 512);
    }
    int lab_row[2][4];
#pragma unroll
    for (int a = 0; a < 2; ++a)
#pragma unroll
        for (int r = 0; r < 4; ++r) lab_row[a][r] = lab[I0 + a * 16 + quad * 4 + r];

    float tacc[2][4] = {};
    float pacc[2][4] = {};

    // Per-tile compute+epilogue, phase 1 (off-diag, no masking, row + col side).
#define TILE_P1(T, BF, LABC)                                                                       \
    {                                                                                              \
        float4v acc0 = {0.f, 0.f, 0.f, 0.f};                                                       \
        float4v acc1 = {0.f, 0.f, 0.f, 0.f};                                                       \
        _Pragma("unroll") for (int s = 0; s < 4; ++s) {                                            \
            acc0 = __builtin_amdgcn_mfma_f32_16x16x32_bf16(afrag[0][s], BF[s], acc0, 0, 0, 0);     \
            acc1 = __builtin_amdgcn_mfma_f32_16x16x32_bf16(afrag[1][s], BF[s], acc1, 0, 0, 0);     \
        }                                                                                          \
        float colTs = 0.f, colPs = 0.f;                                                            \
        _Pragma("unroll") for (int r = 0; r < 4; ++r) {                                            \
            float ex = __builtin_amdgcn_exp2f(acc0[r]);                                            \
            tacc[0][r] += ex;                                                                      \
            float pxe = (lab_row[0][r] == (LABC)) ? ex : 0.f;                                      \
            pacc[0][r] += pxe;                                                                     \
            colTs += ex;                                                                           \
            colPs += pxe;                                                                          \
        }                                                                                          \
        _Pragma("unroll") for (int r = 0; r < 4; ++r) {                                            \
            float ex = __builtin_amdgcn_exp2f(acc1[r]);                                            \
            tacc[1][r] += ex;                                                                      \
            float pxe = (lab_row[1][r] == (LABC)) ? ex : 0.f;                                      \
            pacc[1][r] += pxe;                                                                     \
            colTs += ex;                                                                           \
            colPs += pxe;                                                                          \
        }                                                                                          \
        cpart[wave][T][lane] = make_float2(colTs, colPs);                                          \
    }

    // ---- Phase 1: off-diagonal panel pair, manual 2-deep register pipeline ----
    {
        const unsigned short* bbase = ebfT + ((Jpanel >> 4) * 4 * 64 + lane) * 8;
        short8 bA[4], bB[4];
        int labA, labB;
        labA = lab[Jpanel + lq];
#pragma unroll
        for (int s = 0; s < 4; ++s)
            bA[s] = *reinterpret_cast<const short8*>(bbase + s * 512);
#pragma unroll 1
        for (int t = 0; t < 8; t += 2) {
            // issue loads for tile t+1 BEFORE computing tile t
            labB = lab[Jpanel + (t + 1) * 16 + lq];
            {
                const unsigned short* bt = bbase + (t + 1) * 2048;
#pragma unroll
                for (int s = 0; s < 4; ++s)
                    bB[s] = *reinterpret_cast<const short8*>(bt + s * 512);
            }
            TILE_P1(t, bA, labA);
            // issue loads for tile t+2 (wrapped to 0 on last iter; value unused, stays in-bounds)
            {
                const int tn = (t + 2) & 7;
                labA = lab[Jpanel + tn * 16 + lq];
                const unsigned short* bt = bbase + tn * 2048;
#pragma unroll
                for (int s = 0; s < 4; ++s)
                    bA[s] = *reinterpret_cast<const short8*>(bt + s * 512);
            }
            TILE_P1(t + 1, bB, labB);
        }
    }
#undef TILE_P1

    // ---- Phase 2 (d==1 blocks only): diagonal panel bi, self-masked, row-side only ----
#define TILE_P2(ACCA, ACCB, LABC, J)                                                               \
    {                                                                                              \
        _Pragma("unroll") for (int r = 0; r < 4; ++r) {                                            \
            float ex = __builtin_amdgcn_exp2f(ACCA[r]);                                            \
            if ((J) == I0) ex = (lq == quad * 4 + r) ? 0.f : ex;                                   \
            tacc[0][r] += ex;                                                                      \
            pacc[0][r] += (lab_row[0][r] == (LABC)) ? ex : 0.f;                                    \
        }                                                                                          \
        _Pragma("unroll") for (int r = 0; r < 4; ++r) {                                            \
            float ex = __builtin_amdgcn_exp2f(ACCB[r]);                                            \
            if ((J) == I0 + 16) ex = (lq == quad * 4 + r) ? 0.f : ex;                              \
            tacc[1][r] += ex;                                                                      \
            pacc[1][r] += (lab_row[1][r] == (LABC)) ? ex : 0.f;                                    \
        }                                                                                          \
    }
    if (d == 1) {
        const unsigned short* bbase = ebfT + ((Ipanel >> 4) * 4 * 64 + lane) * 8;
        short8 bA[4], bB[4];
        int labA, labB;
        labA = lab[Ipanel + lq];
#pragma unroll
        for (int s = 0; s < 4; ++s)
            bA[s] = *reinterpret_cast<const short8*>(bbase + s * 512);
#pragma unroll 1
        for (int t = 0; t < 8; t += 2) {
            labB = lab[Ipanel + (t + 1) * 16 + lq];
            {
                const unsigned short* bt = bbase + (t + 1) * 2048;
#pragma unroll
                for (int s = 0; s < 4; ++s)
                    bB[s] = *reinterpret_cast<const short8*>(bt + s * 512);
            }
            {
                float4v acc0 = {0.f, 0.f, 0.f, 0.f};
                float4v acc1 = {0.f, 0.f, 0.f, 0.f};
#pragma unroll
                for (int s = 0; s < 4; ++s) {
                    acc0 = __builtin_amdgcn_mfma_f32_16x16x32_bf16(afrag[0][s], bA[s], acc0, 0, 0, 0);
                    acc1 = __builtin_amdgcn_mfma_f32_16x16x32_bf16(afrag[1][s], bA[s], acc1, 0, 0, 0);
                }
                TILE_P2(acc0, acc1, labA, Ipanel + t * 16);
            }
            {
                const int tn = (t + 2) & 7;
                labA = lab[Ipanel + tn * 16 + lq];
                const unsigned short* bt = bbase + tn * 2048;
#pragma unroll
                for (int s = 0; s < 4; ++s)
                    bA[s] = *reinterpret_cast<const short8*>(bt + s * 512);
            }
            {
                float4v acc0 = {0.f, 0.f, 0.f, 0.f};
                float4v acc1 = {0.f, 0.f, 0.f, 0.f};
#pragma unroll
                for (int s = 0; s < 4; ++s) {
                    acc0 = __builtin_amdgcn_mfma_f32_16x16x32_bf16(afrag[0][s], bB[s], acc0, 0, 0, 0);
                    acc1 = __builtin_amdgcn_mfma_f32_16x16x32_bf16(afrag[1][s], bB[s], acc1, 0, 0, 0);
                }
                TILE_P2(acc0, acc1, labB, Ipanel + (t + 1) * 16);
            }
        }
    }
#undef TILE_P2

    // ---- Row-side flush (covers phase 1 + phase 2): one atomic per row per block ----
    // Register-only + shfl; independent of the barrier, so done BEFORE __syncthreads.
#pragma unroll
    for (int a = 0; a < 2; ++a) {
#pragma unroll
        for (int r = 0; r < 4; ++r) {
            float t = tacc[a][r], p = pacc[a][r];
#pragma unroll
            for (int off = 1; off < 16; off <<= 1) {
                t += __shfl_xor(t, off, 64);
                p += __shfl_xor(p, off, 64);
            }
            if (lq == 0) {
                const int row = I0 + a * 16 + quad * 4 + r;
                atomicAdd(&tot[row], t);
                atomicAdd(&pos[row], p);
            }
        }
    }

    // ---- Col-side gather: sum 4 waves x 4 quads per column, one atomic per column ----
    __syncthreads();
    if (threadIdx.x < 128) {
        const int j = threadIdx.x;          // column within J panel
        const int tt = j >> 4, jl = j & 15; // tile, lane-within-tile
        float st = 0.f, sp = 0.f;
#pragma unroll
        for (int w = 0; w < 4; ++w)
#pragma unroll
            for (int q = 0; q < 4; ++q) {
                float2 v = cpart[w][tt][q * 16 + jl];
                st += v.x;
                sp += v.y;
            }
        atomicAdd(&tot[Jpanel + j], st);
        atomicAdd(&pos[Jpanel + j], sp);
    }
}

// ---------------- Kernel 3: row losses + per-class mean of means ----------------
__global__ __launch_bounds__(1024) void finalize_kernel(const float* __restrict__ pos,
                                                        const float* __restrict__ tot,
                                                        const int* __restrict__ lab,
                                                        float* __restrict__ out) {
    const int tid = threadIdx.x;
    float ls[NUM_CLASSES] = {0.f, 0.f, 0.f, 0.f};
    float lc[NUM_CLASSES] = {0.f, 0.f, 0.f, 0.f};
#pragma unroll
    for (int it = 0; it < N_PIX / 1024; ++it) {
        const int n = it * 1024 + tid;
        float rl = logf(tot[n] + 1e-6f) - logf(pos[n]);
        int c = lab[n];
#pragma unroll
        for (int k = 0; k < NUM_CLASSES; ++k) {
            if (c == k) {
                ls[k] += rl;
                lc[k] += 1.f;
            }
        }
    }
#pragma unroll
    for (int off = 1; off < 64; off <<= 1) {
#pragma unroll
        for (int k = 0; k < NUM_CLASSES; ++k) {
            ls[k] += __shfl_xor(ls[k], off, 64);
            lc[k] += __shfl_xor(lc[k], off, 64);
        }
    }
    __shared__ float ssum[16][NUM_CLASSES];
    __shared__ float scnt[16][NUM_CLASSES];
    const int wid = tid >> 6;
    if ((tid & 63) == 0) {
#pragma unroll
        for (int k = 0; k < NUM_CLASSES; ++k) {
            ssum[wid][k] = ls[k];
            scnt[wid][k] = lc[k];
        }
    }
    __syncthreads();
    if (tid == 0) {
        float acc = 0.f;
        int present = 0;
        for (int k = 0; k < NUM_CLASSES; ++k) {
            float s = 0.f, c = 0.f;
            for (int w = 0; w < 16; ++w) {
                s += ssum[w][k];
                c += scnt[w][k];
            }
            if (c > 0.f) {
                acc += s / c;
                present++;
            }
        }
        out[0] = acc / (float)(present > 0 ? present : 1);
    }
}

extern "C" void kernel_launch(void* const* d_in, const int* in_sizes, int n_in,
                              void* d_out, int out_size, void* d_ws, size_t ws_size,
                              hipStream_t stream) {
    const float* emb = (const float*)d_in[0];  // [2,128,64,64] fp32
    const int* lab = (const int*)d_in[1];      // [2,64,64] int32
    float* out = (float*)d_out;

    unsigned short* ebfT = (unsigned short*)d_ws;            // 2 MiB
    float* pos = (float*)((char*)d_ws + N_PIX * C_DIM * 2);  // [8192] f32
    float* tot = pos + N_PIX;                                // [8192] f32 (contiguous)

    normscale_kernel<<<N_PIX / 16, 256, 0, stream>>>(emb, ebfT, pos);

    dim3 grid(64, 32);  // symmetric panel-pair cover
    pairwise_kernel<<<grid, 256, 0, stream>>>(ebfT, lab, pos, tot);

    finalize_kernel<<<1, 1024, 0, stream>>>(pos, tot, lab, out);
}